// Round 11
// baseline (88.379 us; speedup 1.0000x reference)
//
#include <hip/hip_runtime.h>

#define B_ 32
#define C_ 64
#define T_ 2048
#define TM 128          // q-columns per block (2 waves x 64)
#define TN 64           // s per tile
#define NT (T_ / TN)
#define KWS_BYTES ((size_t)B_ * T_ * 128)          // 8.39 MB bf16 swizzled K
#define WS_NEED (2 * KWS_BYTES)                    // + same for V

typedef __bf16 bf16x8 __attribute__((ext_vector_type(8)));
typedef float f32x4 __attribute__((ext_vector_type(4)));

__device__ __forceinline__ unsigned cvtpk(float lo, float hi) {
  unsigned r;
  asm("v_cvt_pk_bf16_f32 %0, %1, %2" : "=v"(r) : "v"(lo), "v"(hi));
  return r;
}
__device__ __forceinline__ float exp2v(float x) {
  float r;
  asm("v_exp_f32 %0, %1" : "=v"(r) : "v"(x));  // v_exp_f32 = 2^x
  return r;
}
__device__ __forceinline__ void gload16(const char* g, char* l) {
  __builtin_amdgcn_global_load_lds(
      (const __attribute__((address_space(1))) unsigned*)g,
      (__attribute__((address_space(3))) unsigned*)l, 16, 0, 0);
}

// ws layout (all bf16, byte image == R4's proven LDS tiles):
// K: ws + b*T*128 + s*128 + ((((c>>3)^(s&7))&7)<<4) + (c&7)*2
// V: ws + KWS + b*T*128 + (s>>6)*8192 + c*128
//      + (((((sl>>5)*4+((sl>>2)&3)) ^ (c&7))&7)<<4) + ((sl>>4)&1)*8 + (sl&3)*2,  sl=s&63
__global__ __launch_bounds__(256) void prep(const float* __restrict__ qkv,
                                            char* __restrict__ ws) {
  const int gid = blockIdx.x * 256 + threadIdx.x;
  if (gid < B_ * T_) {  // ---- K: thread owns one swizzled 128B row (fixed s) ----
    const int b = gid >> 11, s = gid & 2047;
    const float* kb = qkv + (size_t)b * (3 * C_ * T_) + (size_t)C_ * T_;
    char* row = ws + (size_t)b * (T_ * 128) + s * 128;
#pragma unroll
    for (int oct = 0; oct < 8; ++oct) {  // c-octet: wave-coalesced loads along s
      float v[8];
#pragma unroll
      for (int j = 0; j < 8; ++j) v[j] = kb[(size_t)(oct * 8 + j) * T_ + s];
      uint4 u;
      u.x = cvtpk(v[0], v[1]); u.y = cvtpk(v[2], v[3]);
      u.z = cvtpk(v[4], v[5]); u.w = cvtpk(v[6], v[7]);
      *(uint4*)(row + (((oct ^ (s & 7)) & 7) << 4)) = u;
    }
  } else {  // ---- V: thread owns one tile-row (fixed b, tile k0, c) ----
    const int g2 = gid - B_ * T_;
    const int b = g2 >> 11, rem = g2 & 2047, k0 = rem >> 6, c = rem & 63;
    const float* vp = qkv + (size_t)b * (3 * C_ * T_) + 2 * (size_t)C_ * T_ +
                      (size_t)c * T_ + k0 * 64;
    char* row = ws + KWS_BYTES + (size_t)b * (T_ * 128) + k0 * 8192 + c * 128;
#pragma unroll
    for (int g = 0; g < 16; ++g) {
      const int sl = g * 4;
      const f32x4 v = *(const f32x4*)(vp + sl);
      uint2 u;
      u.x = cvtpk(v[0], v[1]); u.y = cvtpk(v[2], v[3]);
      const int sig = (sl >> 5) * 4 + ((sl >> 2) & 3);
      *(uint2*)(row + (((sig ^ (c & 7)) & 7) << 4) + ((sl >> 4) & 1) * 8) = u;
    }
  }
}

// Main kernel: R4's proven body; staging replaced by async global_load_lds DMA.
__global__ __launch_bounds__(128, 1) void attn11(const float* __restrict__ qkv,
                                                 const char* __restrict__ kws,
                                                 const char* __restrict__ vws,
                                                 float* __restrict__ out) {
  __shared__ __align__(16) char smem[2][2][64 * 128];  // [dbuf][K=0/V=1] 32 KB

  const int tid = threadIdx.x;
  // XCD swizzle: 512 blocks, 8 XCDs -> each XCD owns 4 complete b's
  const int nb = (blockIdx.x & 7) * 64 + (blockIdx.x >> 3);
  const int b = nb >> 4;
  const int t0 = (nb & 15) * TM;

  const float* qb = qkv + (size_t)b * (3 * C_ * T_);
  const float qscale = 0.18033688011112042f;  // (1/8) * log2(e), folded into q

  const int l = tid & 63;
  const int w = tid >> 6;     // wave 0..1
  const int lr = l & 15;
  const int lh = l >> 4;      // 0..3
  const int t0w = t0 + w * 64;

  // iter-invariant read offsets (row-XOR drops out: stride 16 rows == 0 mod 8)
  const int offA = lr * 128 + (((lh ^ (lr & 7)) & 7) << 4);        // K half0 / V m=0
  const int offB = lr * 128 + ((((4 + lh) ^ (lr & 7)) & 7) << 4);  // K half1 / V m=1

  // ---- Q fragments (B-operand), 64 t per wave, hoisted (unchanged from R4) ----
  bf16x8 qf[4][2];
#pragma unroll
  for (int tq = 0; tq < 4; ++tq)
#pragma unroll
    for (int h = 0; h < 2; ++h) {
      float qv[8];
#pragma unroll
      for (int j = 0; j < 8; ++j)
        qv[j] = qb[(size_t)(h * 32 + lh * 8 + j) * T_ + t0w + tq * 16 + lr] * qscale;
      union { unsigned u[4]; bf16x8 v; } tmp;
#pragma unroll
      for (int j = 0; j < 4; ++j) tmp.u[j] = cvtpk(qv[2 * j], qv[2 * j + 1]);
      qf[tq][h] = tmp.v;
    }

  const char* kgb = kws + (size_t)b * (T_ * 128);
  const char* vgb = vws + (size_t)b * (T_ * 128);
  // each wave DMA-copies 4KB of K + 4KB of V per tile (8 x 16B/lane)
  auto stage = [&](int s0, int d) {
    const char* kg = kgb + s0 * 128 + w * 4096 + l * 16;
    const char* vg = vgb + (s0 >> 6) * 8192 + w * 4096 + l * 16;
    char* kl = &smem[d][0][w * 4096];
    char* vl = &smem[d][1][w * 4096];
#pragma unroll
    for (int ch = 0; ch < 4; ++ch) {
      gload16(kg + ch * 1024, kl + ch * 1024);
      gload16(vg + ch * 1024, vl + ch * 1024);
    }
  };

  f32x4 o[4][4];
#pragma unroll
  for (int cf = 0; cf < 4; ++cf)
#pragma unroll
    for (int tq = 0; tq < 4; ++tq) o[cf][tq] = (f32x4){0.f, 0.f, 0.f, 0.f};
  float psum[4] = {0.f, 0.f, 0.f, 0.f};

  stage(0, 0);
  asm volatile("s_waitcnt vmcnt(0)" ::: "memory");
  __syncthreads();

  for (int it = 0; it < NT; ++it) {
    const int d = it & 1;
    const bool pf = (it + 1 < NT);
    const char* Kb = smem[d][0];
    const char* Vb = smem[d][1];

    if (pf) stage((it + 1) * TN, d ^ 1);  // async DMA, overlaps entire compute

    // ---- swapped QK^T: sc[tq][ns] = D[s=16ns+4lh+r][t=t0w+16tq+lr] ----
    f32x4 sc[4][4];
#pragma unroll
    for (int ns = 0; ns < 4; ++ns) {
      const bf16x8 k0 = *(const bf16x8*)(Kb + offA + ns * 2048);
      const bf16x8 k1 = *(const bf16x8*)(Kb + offB + ns * 2048);
#pragma unroll
      for (int tq = 0; tq < 4; ++tq)
        sc[tq][ns] = __builtin_amdgcn_mfma_f32_16x16x32_bf16(
            k0, qf[tq][0], (f32x4){0.f, 0.f, 0.f, 0.f}, 0, 0, 0);
#pragma unroll
      for (int tq = 0; tq < 4; ++tq)
        sc[tq][ns] = __builtin_amdgcn_mfma_f32_16x16x32_bf16(k1, qf[tq][1], sc[tq][ns], 0, 0, 0);
    }

    // ---- no-max softmax (exact by shift-invariance; base-2 via folded scale) ----
    unsigned pd[4][2][4];
#pragma unroll
    for (int tq = 0; tq < 4; ++tq) {
      float a0 = 0.f, a1 = 0.f;
#pragma unroll
      for (int ns = 0; ns < 4; ++ns) {
        f32x4 pv;
#pragma unroll
        for (int r = 0; r < 4; ++r) pv[r] = exp2v(sc[tq][ns][r]);
        pd[tq][ns >> 1][(ns & 1) * 2 + 0] = cvtpk(pv[0], pv[1]);
        pd[tq][ns >> 1][(ns & 1) * 2 + 1] = cvtpk(pv[2], pv[3]);
        if (ns & 1) a1 += (pv[0] + pv[1]) + (pv[2] + pv[3]);
        else        a0 += (pv[0] + pv[1]) + (pv[2] + pv[3]);
      }
      psum[tq] += a0 + a1;
    }

    // ---- PV: O^T[c][t] += V x P; V A-frag = one b128 per (cf,m) ----
#pragma unroll
    for (int cf = 0; cf < 4; ++cf) {
      const bf16x8 vA = *(const bf16x8*)(Vb + offA + cf * 2048);
      const bf16x8 vB = *(const bf16x8*)(Vb + offB + cf * 2048);
#pragma unroll
      for (int tq = 0; tq < 4; ++tq) {
        union { unsigned u[4]; bf16x8 v; } p0;
#pragma unroll
        for (int j = 0; j < 4; ++j) p0.u[j] = pd[tq][0][j];
        o[cf][tq] = __builtin_amdgcn_mfma_f32_16x16x32_bf16(vA, p0.v, o[cf][tq], 0, 0, 0);
      }
#pragma unroll
      for (int tq = 0; tq < 4; ++tq) {
        union { unsigned u[4]; bf16x8 v; } p1;
#pragma unroll
        for (int j = 0; j < 4; ++j) p1.u[j] = pd[tq][1][j];
        o[cf][tq] = __builtin_amdgcn_mfma_f32_16x16x32_bf16(vB, p1.v, o[cf][tq], 0, 0, 0);
      }
    }
    asm volatile("s_waitcnt vmcnt(0)" ::: "memory");
    __syncthreads();
  }

  // ---- epilogue (R4 exact) ----
  float inv[4];
#pragma unroll
  for (int tq = 0; tq < 4; ++tq) {
    float s = psum[tq];
    s += __shfl_xor(s, 16, 64);
    s += __shfl_xor(s, 32, 64);
    inv[tq] = 1.0f / s;
  }
  float* ob = out + (size_t)b * (C_ * T_);
#pragma unroll
  for (int cf = 0; cf < 4; ++cf)
#pragma unroll
    for (int tq = 0; tq < 4; ++tq)
#pragma unroll
      for (int r = 0; r < 4; ++r)
        ob[(size_t)(cf * 16 + lh * 4 + r) * T_ + t0w + tq * 16 + lr] = o[cf][tq][r] * inv[tq];
}

// ---- fallback: R4 kernel verbatim (used only if ws_size < WS_NEED) ----
__global__ __launch_bounds__(128, 1) void attn_fb(const float* __restrict__ qkv,
                                                  float* __restrict__ out) {
  __shared__ __align__(16) char smem[2][2][64 * 128];
  const int tid = threadIdx.x;
  const int nb = (blockIdx.x & 7) * 64 + (blockIdx.x >> 3);
  const int b = nb >> 4;
  const int t0 = (nb & 15) * TM;
  const float* qb = qkv + (size_t)b * (3 * C_ * T_);
  const float* kb = qb + C_ * T_;
  const float* vb = qb + 2 * C_ * T_;
  const float qscale = 0.18033688011112042f;
  const int l = tid & 63;
  const int w = tid >> 6;
  const int lr = l & 15;
  const int lh = l >> 4;
  const int t0w = t0 + w * 64;
  const int offA = lr * 128 + (((lh ^ (lr & 7)) & 7) << 4);
  const int offB = lr * 128 + ((((4 + lh) ^ (lr & 7)) & 7) << 4);
  bf16x8 qf[4][2];
#pragma unroll
  for (int tq = 0; tq < 4; ++tq)
#pragma unroll
    for (int h = 0; h < 2; ++h) {
      float qv[8];
#pragma unroll
      for (int j = 0; j < 8; ++j)
        qv[j] = qb[(size_t)(h * 32 + lh * 8 + j) * T_ + t0w + tq * 16 + lr] * qscale;
      union { unsigned u[4]; bf16x8 v; } tmp;
#pragma unroll
      for (int j = 0; j < 4; ++j) tmp.u[j] = cvtpk(qv[2 * j], qv[2 * j + 1]);
      qf[tq][h] = tmp.v;
    }
  const int cb = (tid >> 4) * 8;
  const int sq4 = (tid & 15) * 4;
  const int sig = (sq4 >> 5) * 4 + ((sq4 >> 2) & 3);
  const int vh8 = ((sq4 >> 4) & 1) * 8;
  f32x4 kreg[8], vreg[8];
  auto loadK = [&](int s0) {
#pragma unroll
    for (int i = 0; i < 8; ++i)
      kreg[i] = *(const f32x4*)(kb + (size_t)(cb + i) * T_ + s0 + sq4);
  };
  auto writeK = [&](int d) {
    char* Kw = smem[d][0];
#pragma unroll
    for (int j = 0; j < 4; ++j) {
      uint4 u;
      u.x = cvtpk(kreg[0][j], kreg[1][j]);
      u.y = cvtpk(kreg[2][j], kreg[3][j]);
      u.z = cvtpk(kreg[4][j], kreg[5][j]);
      u.w = cvtpk(kreg[6][j], kreg[7][j]);
      *(uint4*)(Kw + (sq4 + j) * 128 + ((((cb >> 3) ^ ((sq4 + j) & 7)) & 7) << 4)) = u;
    }
  };
  auto loadV = [&](int s0) {
#pragma unroll
    for (int i = 0; i < 8; ++i)
      vreg[i] = *(const f32x4*)(vb + (size_t)(cb + i) * T_ + s0 + sq4);
  };
  auto writeV = [&](int d) {
    char* Vw = smem[d][1];
#pragma unroll
    for (int i = 0; i < 8; ++i) {
      const int c = cb + i;
      uint2 u;
      u.x = cvtpk(vreg[i][0], vreg[i][1]);
      u.y = cvtpk(vreg[i][2], vreg[i][3]);
      *(uint2*)(Vw + c * 128 + (((sig ^ (c & 7)) & 7) << 4) + vh8) = u;
    }
  };
  f32x4 o[4][4];
#pragma unroll
  for (int cf = 0; cf < 4; ++cf)
#pragma unroll
    for (int tq = 0; tq < 4; ++tq) o[cf][tq] = (f32x4){0.f, 0.f, 0.f, 0.f};
  float psum[4] = {0.f, 0.f, 0.f, 0.f};
  loadK(0); writeK(0); loadV(0); writeV(0);
  __syncthreads();
  for (int it = 0; it < NT; ++it) {
    const int d = it & 1;
    const bool pf = (it + 1 < NT);
    const int s1 = (it + 1) * TN;
    const char* Kb = smem[d][0];
    const char* Vb = smem[d][1];
    if (pf) loadK(s1);
    f32x4 sc[4][4];
#pragma unroll
    for (int ns = 0; ns < 4; ++ns) {
      const bf16x8 k0 = *(const bf16x8*)(Kb + offA + ns * 2048);
      const bf16x8 k1 = *(const bf16x8*)(Kb + offB + ns * 2048);
#pragma unroll
      for (int tq = 0; tq < 4; ++tq)
        sc[tq][ns] = __builtin_amdgcn_mfma_f32_16x16x32_bf16(
            k0, qf[tq][0], (f32x4){0.f, 0.f, 0.f, 0.f}, 0, 0, 0);
#pragma unroll
      for (int tq = 0; tq < 4; ++tq)
        sc[tq][ns] = __builtin_amdgcn_mfma_f32_16x16x32_bf16(k1, qf[tq][1], sc[tq][ns], 0, 0, 0);
    }
    if (pf) { writeK(d ^ 1); loadV(s1); }
    unsigned pd[4][2][4];
#pragma unroll
    for (int tq = 0; tq < 4; ++tq) {
      float a0 = 0.f, a1 = 0.f;
#pragma unroll
      for (int ns = 0; ns < 4; ++ns) {
        f32x4 pv;
#pragma unroll
        for (int r = 0; r < 4; ++r) pv[r] = exp2v(sc[tq][ns][r]);
        pd[tq][ns >> 1][(ns & 1) * 2 + 0] = cvtpk(pv[0], pv[1]);
        pd[tq][ns >> 1][(ns & 1) * 2 + 1] = cvtpk(pv[2], pv[3]);
        if (ns & 1) a1 += (pv[0] + pv[1]) + (pv[2] + pv[3]);
        else        a0 += (pv[0] + pv[1]) + (pv[2] + pv[3]);
      }
      psum[tq] += a0 + a1;
    }
    if (pf) writeV(d ^ 1);
#pragma unroll
    for (int cf = 0; cf < 4; ++cf) {
      const bf16x8 vA = *(const bf16x8*)(Vb + offA + cf * 2048);
      const bf16x8 vB = *(const bf16x8*)(Vb + offB + cf * 2048);
#pragma unroll
      for (int tq = 0; tq < 4; ++tq) {
        union { unsigned u[4]; bf16x8 v; } p0;
#pragma unroll
        for (int j = 0; j < 4; ++j) p0.u[j] = pd[tq][0][j];
        o[cf][tq] = __builtin_amdgcn_mfma_f32_16x16x32_bf16(vA, p0.v, o[cf][tq], 0, 0, 0);
      }
#pragma unroll
      for (int tq = 0; tq < 4; ++tq) {
        union { unsigned u[4]; bf16x8 v; } p1;
#pragma unroll
        for (int j = 0; j < 4; ++j) p1.u[j] = pd[tq][1][j];
        o[cf][tq] = __builtin_amdgcn_mfma_f32_16x16x32_bf16(vB, p1.v, o[cf][tq], 0, 0, 0);
      }
    }
    __syncthreads();
  }
  float inv[4];
#pragma unroll
  for (int tq = 0; tq < 4; ++tq) {
    float s = psum[tq];
    s += __shfl_xor(s, 16, 64);
    s += __shfl_xor(s, 32, 64);
    inv[tq] = 1.0f / s;
  }
  float* ob = out + (size_t)b * (C_ * T_);
#pragma unroll
  for (int cf = 0; cf < 4; ++cf)
#pragma unroll
    for (int tq = 0; tq < 4; ++tq)
#pragma unroll
      for (int r = 0; r < 4; ++r)
        ob[(size_t)(cf * 16 + lh * 4 + r) * T_ + t0w + tq * 16 + lr] = o[cf][tq][r] * inv[tq];
}

extern "C" void kernel_launch(void* const* d_in, const int* in_sizes, int n_in,
                              void* d_out, int out_size, void* d_ws, size_t ws_size,
                              hipStream_t stream) {
  const float* qkv = (const float*)d_in[0];
  float* out = (float*)d_out;
  if (ws_size >= WS_NEED) {
    char* ws = (char*)d_ws;
    hipLaunchKernelGGL(prep, dim3(2 * B_ * T_ / 256), dim3(256), 0, stream, qkv, ws);
    hipLaunchKernelGGL(attn11, dim3((T_ / TM) * B_), dim3(128), 0, stream, qkv,
                       (const char*)ws, (const char*)(ws + KWS_BYTES), out);
  } else {
    hipLaunchKernelGGL(attn_fb, dim3((T_ / TM) * B_), dim3(128), 0, stream, qkv, out);
  }
}

// Round 12
// 66.733 us; speedup vs baseline: 1.3244x; 1.3244x over previous
//
#include <hip/hip_runtime.h>

#define B_ 32
#define C_ 64
#define T_ 2048
#define TM 64           // q-columns per block (2 waves x 32)
#define TN 64           // s per tile
#define NT (T_ / TN)
#define KWS_BYTES ((size_t)B_ * T_ * 128)          // 8.39 MB bf16 swizzled K
#define WS_NEED (2 * KWS_BYTES)                    // + same for V

typedef __bf16 bf16x8 __attribute__((ext_vector_type(8)));
typedef float f32x4 __attribute__((ext_vector_type(4)));

__device__ __forceinline__ unsigned cvtpk(float lo, float hi) {
  unsigned r;
  asm("v_cvt_pk_bf16_f32 %0, %1, %2" : "=v"(r) : "v"(lo), "v"(hi));
  return r;
}
__device__ __forceinline__ float exp2v(float x) {
  float r;
  asm("v_exp_f32 %0, %1" : "=v"(r) : "v"(x));  // v_exp_f32 = 2^x
  return r;
}
__device__ __forceinline__ void gload16(const char* g, char* l) {
  __builtin_amdgcn_global_load_lds(
      (const __attribute__((address_space(1))) unsigned*)g,
      (__attribute__((address_space(3))) unsigned*)l, 16, 0, 0);
}

// ws layout (all bf16, byte image == R4's proven LDS tiles):
// K: ws + b*T*128 + s*128 + ((((c>>3)^(s&7))&7)<<4) + (c&7)*2
// V: ws + KWS + b*T*128 + (s>>6)*8192 + c*128
//      + (((((sl>>5)*4+((sl>>2)&3)) ^ (c&7))&7)<<4) + ((sl>>4)&1)*8 + (sl&3)*2,  sl=s&63
__global__ __launch_bounds__(256) void prep(const float* __restrict__ qkv,
                                            char* __restrict__ ws) {
  const int gid = blockIdx.x * 256 + threadIdx.x;
  if (gid < B_ * T_) {  // ---- K: thread owns one swizzled 128B row (fixed s) ----
    const int b = gid >> 11, s = gid & 2047;
    const float* kb = qkv + (size_t)b * (3 * C_ * T_) + (size_t)C_ * T_;
    char* row = ws + (size_t)b * (T_ * 128) + s * 128;
#pragma unroll
    for (int oct = 0; oct < 8; ++oct) {  // c-octet: wave-coalesced loads along s
      float v[8];
#pragma unroll
      for (int j = 0; j < 8; ++j) v[j] = kb[(size_t)(oct * 8 + j) * T_ + s];
      uint4 u;
      u.x = cvtpk(v[0], v[1]); u.y = cvtpk(v[2], v[3]);
      u.z = cvtpk(v[4], v[5]); u.w = cvtpk(v[6], v[7]);
      *(uint4*)(row + (((oct ^ (s & 7)) & 7) << 4)) = u;
    }
  } else {  // ---- V: thread owns one tile-row (fixed b, tile k0, c) ----
    const int g2 = gid - B_ * T_;
    const int b = g2 >> 11, rem = g2 & 2047, k0 = rem >> 6, c = rem & 63;
    const float* vp = qkv + (size_t)b * (3 * C_ * T_) + 2 * (size_t)C_ * T_ +
                      (size_t)c * T_ + k0 * 64;
    char* row = ws + KWS_BYTES + (size_t)b * (T_ * 128) + k0 * 8192 + c * 128;
#pragma unroll
    for (int g = 0; g < 16; ++g) {
      const int sl = g * 4;
      const f32x4 v = *(const f32x4*)(vp + sl);
      uint2 u;
      u.x = cvtpk(v[0], v[1]); u.y = cvtpk(v[2], v[3]);
      const int sig = (sl >> 5) * 4 + ((sl >> 2) & 3);
      *(uint2*)(row + (((sig ^ (c & 7)) & 7) << 4) + ((sl >> 4) & 1) * 8) = u;
    }
  }
}

// Main kernel: R9's proven TM=64 compute shapes + R11's proven DMA staging.
// 1024 blocks = 4 blocks/CU x 2 waves = 8 waves/CU (2/SIMD).
__global__ __launch_bounds__(128, 1) void attn12(const float* __restrict__ qkv,
                                                 const char* __restrict__ kws,
                                                 const char* __restrict__ vws,
                                                 float* __restrict__ out) {
  __shared__ __align__(16) char smem[2][2][64 * 128];  // [dbuf][K=0/V=1] 32 KB

  const int tid = threadIdx.x;
  // XCD swizzle (bijective, grid 1024): each XCD owns 128 consecutive nb = 4 b's
  const int nb = (blockIdx.x & 7) * 128 + (blockIdx.x >> 3);
  const int b = nb >> 5;
  const int t0 = (nb & 31) * TM;

  const float* qb = qkv + (size_t)b * (3 * C_ * T_);
  const float qscale = 0.18033688011112042f;  // (1/8) * log2(e), folded into q

  const int l = tid & 63;
  const int w = tid >> 6;     // wave 0..1
  const int lr = l & 15;
  const int lh = l >> 4;      // 0..3
  const int t0w = t0 + w * 32;

  // iter-invariant read offsets (row-XOR drops out: stride 16 rows == 0 mod 8)
  const int offA = lr * 128 + (((lh ^ (lr & 7)) & 7) << 4);        // K half0 / V m=0
  const int offB = lr * 128 + ((((4 + lh) ^ (lr & 7)) & 7) << 4);  // K half1 / V m=1

  // ---- Q fragments (B-operand), 32 t per wave, hoisted (R9 exact) ----
  bf16x8 qf[2][2];
#pragma unroll
  for (int tq = 0; tq < 2; ++tq)
#pragma unroll
    for (int h = 0; h < 2; ++h) {
      float qv[8];
#pragma unroll
      for (int j = 0; j < 8; ++j)
        qv[j] = qb[(size_t)(h * 32 + lh * 8 + j) * T_ + t0w + tq * 16 + lr] * qscale;
      union { unsigned u[4]; bf16x8 v; } tmp;
#pragma unroll
      for (int j = 0; j < 4; ++j) tmp.u[j] = cvtpk(qv[2 * j], qv[2 * j + 1]);
      qf[tq][h] = tmp.v;
    }

  const char* kgb = kws + (size_t)b * (T_ * 128);
  const char* vgb = vws + (size_t)b * (T_ * 128);
  // each wave DMA-copies 4KB of K + 4KB of V per tile (8 x 16B/lane)  (R11 exact)
  auto stage = [&](int s0, int d) {
    const char* kg = kgb + s0 * 128 + w * 4096 + l * 16;
    const char* vg = vgb + (s0 >> 6) * 8192 + w * 4096 + l * 16;
    char* kl = &smem[d][0][w * 4096];
    char* vl = &smem[d][1][w * 4096];
#pragma unroll
    for (int ch = 0; ch < 4; ++ch) {
      gload16(kg + ch * 1024, kl + ch * 1024);
      gload16(vg + ch * 1024, vl + ch * 1024);
    }
  };

  f32x4 o[4][2];
#pragma unroll
  for (int cf = 0; cf < 4; ++cf)
#pragma unroll
    for (int tq = 0; tq < 2; ++tq) o[cf][tq] = (f32x4){0.f, 0.f, 0.f, 0.f};
  float psum[2] = {0.f, 0.f};

  stage(0, 0);
  asm volatile("s_waitcnt vmcnt(0)" ::: "memory");
  __syncthreads();

  for (int it = 0; it < NT; ++it) {
    const int d = it & 1;
    const bool pf = (it + 1 < NT);
    const char* Kb = smem[d][0];
    const char* Vb = smem[d][1];

    if (pf) stage((it + 1) * TN, d ^ 1);  // async DMA, overlaps entire compute

    // ---- swapped QK^T: sc[tq][ns] = D[s=16ns+4lh+r][t=t0w+16tq+lr] ----
    f32x4 sc[2][4];
#pragma unroll
    for (int ns = 0; ns < 4; ++ns) {
      const bf16x8 k0 = *(const bf16x8*)(Kb + offA + ns * 2048);
      const bf16x8 k1 = *(const bf16x8*)(Kb + offB + ns * 2048);
#pragma unroll
      for (int tq = 0; tq < 2; ++tq)
        sc[tq][ns] = __builtin_amdgcn_mfma_f32_16x16x32_bf16(
            k0, qf[tq][0], (f32x4){0.f, 0.f, 0.f, 0.f}, 0, 0, 0);
#pragma unroll
      for (int tq = 0; tq < 2; ++tq)
        sc[tq][ns] = __builtin_amdgcn_mfma_f32_16x16x32_bf16(k1, qf[tq][1], sc[tq][ns], 0, 0, 0);
    }

    // ---- no-max softmax (exact by shift-invariance; base-2 via folded scale) ----
    unsigned pd[2][2][4];
#pragma unroll
    for (int tq = 0; tq < 2; ++tq) {
      float a0 = 0.f, a1 = 0.f;
#pragma unroll
      for (int ns = 0; ns < 4; ++ns) {
        f32x4 pv;
#pragma unroll
        for (int r = 0; r < 4; ++r) pv[r] = exp2v(sc[tq][ns][r]);
        pd[tq][ns >> 1][(ns & 1) * 2 + 0] = cvtpk(pv[0], pv[1]);
        pd[tq][ns >> 1][(ns & 1) * 2 + 1] = cvtpk(pv[2], pv[3]);
        if (ns & 1) a1 += (pv[0] + pv[1]) + (pv[2] + pv[3]);
        else        a0 += (pv[0] + pv[1]) + (pv[2] + pv[3]);
      }
      psum[tq] += a0 + a1;
    }

    // ---- PV: O^T[c][t] += V x P; V A-frag = one b128 per (cf,m) ----
#pragma unroll
    for (int cf = 0; cf < 4; ++cf) {
      const bf16x8 vA = *(const bf16x8*)(Vb + offA + cf * 2048);
      const bf16x8 vB = *(const bf16x8*)(Vb + offB + cf * 2048);
#pragma unroll
      for (int tq = 0; tq < 2; ++tq) {
        union { unsigned u[4]; bf16x8 v; } p0;
#pragma unroll
        for (int j = 0; j < 4; ++j) p0.u[j] = pd[tq][0][j];
        o[cf][tq] = __builtin_amdgcn_mfma_f32_16x16x32_bf16(vA, p0.v, o[cf][tq], 0, 0, 0);
      }
#pragma unroll
      for (int tq = 0; tq < 2; ++tq) {
        union { unsigned u[4]; bf16x8 v; } p1;
#pragma unroll
        for (int j = 0; j < 4; ++j) p1.u[j] = pd[tq][1][j];
        o[cf][tq] = __builtin_amdgcn_mfma_f32_16x16x32_bf16(vB, p1.v, o[cf][tq], 0, 0, 0);
      }
    }
    asm volatile("s_waitcnt vmcnt(0)" ::: "memory");
    __syncthreads();
  }

  // ---- epilogue (R9 exact) ----
  float inv[2];
#pragma unroll
  for (int tq = 0; tq < 2; ++tq) {
    float s = psum[tq];
    s += __shfl_xor(s, 16, 64);
    s += __shfl_xor(s, 32, 64);
    inv[tq] = 1.0f / s;
  }
  float* ob = out + (size_t)b * (C_ * T_);
#pragma unroll
  for (int cf = 0; cf < 4; ++cf)
#pragma unroll
    for (int tq = 0; tq < 2; ++tq)
#pragma unroll
      for (int r = 0; r < 4; ++r)
        ob[(size_t)(cf * 16 + lh * 4 + r) * T_ + t0w + tq * 16 + lr] = o[cf][tq][r] * inv[tq];
}

// ---- fallback: R4 kernel verbatim (used only if ws_size < WS_NEED) ----
__global__ __launch_bounds__(128, 1) void attn_fb(const float* __restrict__ qkv,
                                                  float* __restrict__ out) {
  __shared__ __align__(16) char smem[2][2][64 * 128];
  const int tid = threadIdx.x;
  const int nb = (blockIdx.x & 7) * 64 + (blockIdx.x >> 3);
  const int b = nb >> 4;
  const int t0 = (nb & 15) * 128;
  const float* qb = qkv + (size_t)b * (3 * C_ * T_);
  const float* kb = qb + C_ * T_;
  const float* vb = qb + 2 * C_ * T_;
  const float qscale = 0.18033688011112042f;
  const int l = tid & 63;
  const int w = tid >> 6;
  const int lr = l & 15;
  const int lh = l >> 4;
  const int t0w = t0 + w * 64;
  const int offA = lr * 128 + (((lh ^ (lr & 7)) & 7) << 4);
  const int offB = lr * 128 + ((((4 + lh) ^ (lr & 7)) & 7) << 4);
  bf16x8 qf[4][2];
#pragma unroll
  for (int tq = 0; tq < 4; ++tq)
#pragma unroll
    for (int h = 0; h < 2; ++h) {
      float qv[8];
#pragma unroll
      for (int j = 0; j < 8; ++j)
        qv[j] = qb[(size_t)(h * 32 + lh * 8 + j) * T_ + t0w + tq * 16 + lr] * qscale;
      union { unsigned u[4]; bf16x8 v; } tmp;
#pragma unroll
      for (int j = 0; j < 4; ++j) tmp.u[j] = cvtpk(qv[2 * j], qv[2 * j + 1]);
      qf[tq][h] = tmp.v;
    }
  const int cb = (tid >> 4) * 8;
  const int sq4 = (tid & 15) * 4;
  const int sig = (sq4 >> 5) * 4 + ((sq4 >> 2) & 3);
  const int vh8 = ((sq4 >> 4) & 1) * 8;
  f32x4 kreg[8], vreg[8];
  auto loadK = [&](int s0) {
#pragma unroll
    for (int i = 0; i < 8; ++i)
      kreg[i] = *(const f32x4*)(kb + (size_t)(cb + i) * T_ + s0 + sq4);
  };
  auto writeK = [&](int d) {
    char* Kw = smem[d][0];
#pragma unroll
    for (int j = 0; j < 4; ++j) {
      uint4 u;
      u.x = cvtpk(kreg[0][j], kreg[1][j]);
      u.y = cvtpk(kreg[2][j], kreg[3][j]);
      u.z = cvtpk(kreg[4][j], kreg[5][j]);
      u.w = cvtpk(kreg[6][j], kreg[7][j]);
      *(uint4*)(Kw + (sq4 + j) * 128 + ((((cb >> 3) ^ ((sq4 + j) & 7)) & 7) << 4)) = u;
    }
  };
  auto loadV = [&](int s0) {
#pragma unroll
    for (int i = 0; i < 8; ++i)
      vreg[i] = *(const f32x4*)(vb + (size_t)(cb + i) * T_ + s0 + sq4);
  };
  auto writeV = [&](int d) {
    char* Vw = smem[d][1];
#pragma unroll
    for (int i = 0; i < 8; ++i) {
      const int c = cb + i;
      uint2 u;
      u.x = cvtpk(vreg[i][0], vreg[i][1]);
      u.y = cvtpk(vreg[i][2], vreg[i][3]);
      *(uint2*)(Vw + c * 128 + (((sig ^ (c & 7)) & 7) << 4) + vh8) = u;
    }
  };
  f32x4 o[4][4];
#pragma unroll
  for (int cf = 0; cf < 4; ++cf)
#pragma unroll
    for (int tq = 0; tq < 4; ++tq) o[cf][tq] = (f32x4){0.f, 0.f, 0.f, 0.f};
  float psum[4] = {0.f, 0.f, 0.f, 0.f};
  loadK(0); writeK(0); loadV(0); writeV(0);
  __syncthreads();
  for (int it = 0; it < NT; ++it) {
    const int d = it & 1;
    const bool pf = (it + 1 < NT);
    const int s1 = (it + 1) * TN;
    const char* Kb = smem[d][0];
    const char* Vb = smem[d][1];
    if (pf) loadK(s1);
    f32x4 sc[4][4];
#pragma unroll
    for (int ns = 0; ns < 4; ++ns) {
      const bf16x8 k0 = *(const bf16x8*)(Kb + offA + ns * 2048);
      const bf16x8 k1 = *(const bf16x8*)(Kb + offB + ns * 2048);
#pragma unroll
      for (int tq = 0; tq < 4; ++tq)
        sc[tq][ns] = __builtin_amdgcn_mfma_f32_16x16x32_bf16(
            k0, qf[tq][0], (f32x4){0.f, 0.f, 0.f, 0.f}, 0, 0, 0);
#pragma unroll
      for (int tq = 0; tq < 4; ++tq)
        sc[tq][ns] = __builtin_amdgcn_mfma_f32_16x16x32_bf16(k1, qf[tq][1], sc[tq][ns], 0, 0, 0);
    }
    if (pf) { writeK(d ^ 1); loadV(s1); }
    unsigned pd[4][2][4];
#pragma unroll
    for (int tq = 0; tq < 4; ++tq) {
      float a0 = 0.f, a1 = 0.f;
#pragma unroll
      for (int ns = 0; ns < 4; ++ns) {
        f32x4 pv;
#pragma unroll
        for (int r = 0; r < 4; ++r) pv[r] = exp2v(sc[tq][ns][r]);
        pd[tq][ns >> 1][(ns & 1) * 2 + 0] = cvtpk(pv[0], pv[1]);
        pd[tq][ns >> 1][(ns & 1) * 2 + 1] = cvtpk(pv[2], pv[3]);
        if (ns & 1) a1 += (pv[0] + pv[1]) + (pv[2] + pv[3]);
        else        a0 += (pv[0] + pv[1]) + (pv[2] + pv[3]);
      }
      psum[tq] += a0 + a1;
    }
    if (pf) writeV(d ^ 1);
#pragma unroll
    for (int cf = 0; cf < 4; ++cf) {
      const bf16x8 vA = *(const bf16x8*)(Vb + offA + cf * 2048);
      const bf16x8 vB = *(const bf16x8*)(Vb + offB + cf * 2048);
#pragma unroll
      for (int tq = 0; tq < 4; ++tq) {
        union { unsigned u[4]; bf16x8 v; } p0;
#pragma unroll
        for (int j = 0; j < 4; ++j) p0.u[j] = pd[tq][0][j];
        o[cf][tq] = __builtin_amdgcn_mfma_f32_16x16x32_bf16(vA, p0.v, o[cf][tq], 0, 0, 0);
      }
#pragma unroll
      for (int tq = 0; tq < 4; ++tq) {
        union { unsigned u[4]; bf16x8 v; } p1;
#pragma unroll
        for (int j = 0; j < 4; ++j) p1.u[j] = pd[tq][1][j];
        o[cf][tq] = __builtin_amdgcn_mfma_f32_16x16x32_bf16(vB, p1.v, o[cf][tq], 0, 0, 0);
      }
    }
    __syncthreads();
  }
  float inv[4];
#pragma unroll
  for (int tq = 0; tq < 4; ++tq) {
    float s = psum[tq];
    s += __shfl_xor(s, 16, 64);
    s += __shfl_xor(s, 32, 64);
    inv[tq] = 1.0f / s;
  }
  float* ob = out + (size_t)b * (C_ * T_);
#pragma unroll
  for (int cf = 0; cf < 4; ++cf)
#pragma unroll
    for (int tq = 0; tq < 4; ++tq)
#pragma unroll
      for (int r = 0; r < 4; ++r)
        ob[(size_t)(cf * 16 + lh * 4 + r) * T_ + t0w + tq * 16 + lr] = o[cf][tq][r] * inv[tq];
}

extern "C" void kernel_launch(void* const* d_in, const int* in_sizes, int n_in,
                              void* d_out, int out_size, void* d_ws, size_t ws_size,
                              hipStream_t stream) {
  const float* qkv = (const float*)d_in[0];
  float* out = (float*)d_out;
  if (ws_size >= WS_NEED) {
    char* ws = (char*)d_ws;
    hipLaunchKernelGGL(prep, dim3(2 * B_ * T_ / 256), dim3(256), 0, stream, qkv, ws);
    hipLaunchKernelGGL(attn12, dim3((T_ / TM) * B_), dim3(128), 0, stream, qkv,
                       (const char*)ws, (const char*)(ws + KWS_BYTES), out);
  } else {
    hipLaunchKernelGGL(attn_fb, dim3(512), dim3(128), 0, stream, qkv, out);
  }
}